// Round 1
// baseline (402.174 us; speedup 1.0000x reference)
//
#include <hip/hip_runtime.h>
#include <hip/hip_bf16.h>
#include <stdint.h>

#define DFEAT 256
#define NPTS  8192

typedef __attribute__((ext_vector_type(8)))  short bf16x8;   // 8 bf16 = 4 VGPRs
typedef __attribute__((ext_vector_type(16))) float f32x16;   // 32x32 C/D
typedef __attribute__((ext_vector_type(4)))  int   int4v;

#define AS1 __attribute__((address_space(1)))
#define AS3 __attribute__((address_space(3)))

__device__ inline void dma16(const void* g, void* l) {
  // async global->LDS, 16B per lane; LDS dest = wave-uniform base + lane*16
  __builtin_amdgcn_global_load_lds((const AS1 uint32_t*)g, (AS3 uint32_t*)l, 16, 0, 0);
}

__device__ inline uint16_t f2bf(float f) {  // RNE fp32->bf16
  union { float f; uint32_t u; } v; v.f = f;
  return (uint16_t)((v.u + 0x7FFFu + ((v.u >> 16) & 1u)) >> 16);
}

// ---------------------------------------------------------------------------
// Fused flash-style mean-shift step: for m-tile (64 cols), loop n (steps 64):
//   S[n,m] = Xn^T Xm  (k=d=256, bf16 MFMA) ; P = exp(6S)
//   CS[m] += colsum(P) ; O[d,m] += Xn P  (k=n)
// grid = 128 m-tiles x 4 n-splits; partials merged via fp32 atomics.
// ---------------------------------------------------------------------------
__global__ __launch_bounds__(256, 2) void ms_fused(
    const uint16_t* __restrict__ xb,   // bf16 X  [256][8192]
    const uint16_t* __restrict__ xtb,  // bf16 X^T [8192][256]
    float* __restrict__ num,           // [256][8192] fp32, pre-zeroed
    float* __restrict__ cs)            // [8192] fp32, pre-zeroed
{
  __shared__ __attribute__((aligned(16))) uint16_t Xn [DFEAT*64];   // [d][n] rows 128B, swizzled
  __shared__ __attribute__((aligned(16))) uint16_t XTn[64*DFEAT];   // [n][d] rows 512B, swizzled
  __shared__ __attribute__((aligned(16))) uint16_t Ps [4*64*18];    // [ks][m][16+2 pad]

  const int tid  = threadIdx.x;
  const int w    = tid >> 6;
  const int lane = tid & 63;
  const int l31  = lane & 31;
  const int g    = lane >> 5;
  const int m0   = (blockIdx.x >> 2) * 64;   // m-tile base
  const int q    = blockIdx.x & 3;           // n-split
  const int a_sub = w >> 1;                  // S n-sub (0/1)
  const int b_sub = w & 1;                   // S m-sub (0/1)

  // Xm B-fragments (B[k=d][col=m]): row m of X^T, kept in registers (64 VGPRs)
  bf16x8 Bm[16];
  {
    const uint16_t* mrow = xtb + (size_t)(m0 + 32*b_sub + l31) * DFEAT;
    #pragma unroll
    for (int ks = 0; ks < 16; ++ks)
      Bm[ks] = __builtin_bit_cast(bf16x8, *(const int4v*)(mrow + ks*16 + g*8));
  }

  f32x16 accO[2][2];
  #pragma unroll
  for (int i = 0; i < 2; ++i)
    #pragma unroll
    for (int j = 0; j < 2; ++j)
      #pragma unroll
      for (int r = 0; r < 16; ++r) accO[i][j][r] = 0.0f;
  float csacc = 0.0f;

  // staging lane constants (r-independent thanks to 32r / 8r strides)
  const int xn_d0   = tid >> 3;                               // + 32*r
  const int xn_noff = ((tid & 7) ^ ((tid >> 3) & 7)) * 8;     // swizzled chunk

  for (int t = 0; t < 32; ++t) {
    const int n0 = q * 2048 + t * 64;
    __syncthreads();  // previous PV done before LDS overwrite

    // stage Xn [256][64]: chunk c holds global chunk (c&7)^(d&7) of row d
    #pragma unroll
    for (int r = 0; r < 8; ++r) {
      const uint16_t* gp = xb + (size_t)(xn_d0 + 32*r) * NPTS + n0 + xn_noff;
      dma16(gp, (char*)Xn + (r*256 + tid) * 16);
    }
    // stage XTn [64][256]: slot (n, c&31) holds global chunk (c&31)^(n&31)
    #pragma unroll
    for (int r = 0; r < 8; ++r) {
      int c    = r*256 + tid;
      int nrow = c >> 5;
      int cd   = (c & 31) ^ (nrow & 31);
      const uint16_t* gp = xtb + (size_t)(n0 + nrow) * DFEAT + cd * 8;
      dma16(gp, (char*)XTn + c * 16);
    }
    __syncthreads();

    // ---- S = Xn^T Xm (wave quadrant: n-sub a_sub, m-sub b_sub) ----
    f32x16 s;
    #pragma unroll
    for (int r = 0; r < 16; ++r) s[r] = 0.0f;
    {
      const char* arow = (const char*)XTn + (32*a_sub + l31) * 512;
      #pragma unroll
      for (int ks = 0; ks < 16; ++ks) {
        int slot = (2*ks + g) ^ l31;  // undo swizzle (n&31 == l31)
        bf16x8 A = __builtin_bit_cast(bf16x8, *(const int4v*)(arow + slot*16));
        s = __builtin_amdgcn_mfma_f32_32x32x16_bf16(A, Bm[ks], s, 0, 0, 0);
      }
    }
    // ---- P = exp(6S); colsum partial; write P to LDS k-slices ----
    {
      const int mloc = 32*b_sub + l31;
      #pragma unroll
      for (int r = 0; r < 16; ++r) {
        float e = __expf(6.0f * s[r]);
        s[r] = e;
        csacc += e;
      }
      #pragma unroll
      for (int j = 0; j < 8; ++j) {   // reg pairs (2j,2j+1) = consecutive n
        int nn = 32*a_sub + ((2*j) & 3) + 8*((2*j) >> 2) + 4*g;
        uint32_t pk = (uint32_t)f2bf(s[2*j]) | ((uint32_t)f2bf(s[2*j+1]) << 16);
        *(uint32_t*)((char*)Ps + (nn >> 4)*2304 + mloc*36 + (nn & 15)*2) = pk;
      }
    }
    __syncthreads();  // P complete (cross-wave use)

    // ---- O[d,m] += Xn * P  (wave: d-tiles {2w,2w+1}, both m-subs) ----
    #pragma unroll
    for (int ks = 0; ks < 4; ++ks) {
      bf16x8 Bp[2];
      #pragma unroll
      for (int mm = 0; mm < 2; ++mm) {
        const char* base = (const char*)Ps + ks*2304 + (32*mm + l31)*36 + g*16;
        union { uint32_t u[4]; bf16x8 v; } tb;
        tb.u[0] = *(const uint32_t*)(base);
        tb.u[1] = *(const uint32_t*)(base + 4);
        tb.u[2] = *(const uint32_t*)(base + 8);
        tb.u[3] = *(const uint32_t*)(base + 12);
        Bp[mm] = tb.v;
      }
      #pragma unroll
      for (int t2 = 0; t2 < 2; ++t2) {
        const int drow = 32*(2*w + t2) + l31;
        int slot = (2*ks + g) ^ (l31 & 7);  // undo swizzle (d&7 == l31&7)
        bf16x8 A = __builtin_bit_cast(bf16x8,
            *(const int4v*)((const char*)Xn + drow*128 + slot*16));
        accO[t2][0] = __builtin_amdgcn_mfma_f32_32x32x16_bf16(A, Bp[0], accO[t2][0], 0,0,0);
        accO[t2][1] = __builtin_amdgcn_mfma_f32_32x32x16_bf16(A, Bp[1], accO[t2][1], 0,0,0);
      }
    }
  }

  // ---- epilogue: merge partials ----
  csacc += __shfl_xor(csacc, 32, 64);
  if (g == 0) atomicAdd(&cs[m0 + 32*b_sub + l31], csacc);
  #pragma unroll
  for (int t2 = 0; t2 < 2; ++t2)
    #pragma unroll
    for (int mm = 0; mm < 2; ++mm)
      #pragma unroll
      for (int r = 0; r < 16; ++r) {
        int drow = 32*(2*w + t2) + (r & 3) + 8*(r >> 2) + 4*g;
        int mg   = m0 + 32*mm + l31;
        atomicAdd(&num[(size_t)drow * NPTS + mg], accO[t2][mm][r]);
      }
}

// ---------------------------------------------------------------------------
// Combine: mode 1: Y = Num / CS -> d_out slice + bf16 X / X^T for next iter.
//          mode 0: just convert fp32 src -> bf16 X / X^T (initial X).
// ---------------------------------------------------------------------------
__global__ __launch_bounds__(256) void ms_combine(
    const float* __restrict__ src, const float* __restrict__ cs,
    float* __restrict__ yout, uint16_t* __restrict__ xbo, uint16_t* __restrict__ xto,
    const int mode)
{
  __shared__ uint16_t T[64][66];
  const int tid = threadIdx.x;
  const int n0 = blockIdx.x * 64;
  const int d0 = blockIdx.y * 64;
  #pragma unroll
  for (int i = 0; i < 16; ++i) {
    int e  = tid + i*256;
    int dl = e >> 6, nl = e & 63;
    size_t idx = (size_t)(d0 + dl) * NPTS + (n0 + nl);
    float v = src[idx];
    if (mode) { v /= cs[n0 + nl]; yout[idx] = v; }
    uint16_t b = f2bf(v);
    xbo[idx] = b;
    T[dl][nl] = b;
  }
  __syncthreads();
  #pragma unroll
  for (int i = 0; i < 8; ++i) {
    int p  = tid + i*256;
    int nl = p >> 5, dp = p & 31;
    uint32_t pk = (uint32_t)T[2*dp][nl] | ((uint32_t)T[2*dp+1][nl] << 16);
    ((uint32_t*)xto)[(((size_t)(n0 + nl) * DFEAT + d0) >> 1) + dp] = pk;
  }
}

extern "C" void kernel_launch(void* const* d_in, const int* in_sizes, int n_in,
                              void* d_out, int out_size, void* d_ws, size_t ws_size,
                              hipStream_t stream)
{
  (void)in_sizes; (void)n_in; (void)out_size; (void)ws_size;
  const float* X = (const float*)d_in[0];
  float* out = (float*)d_out;
  char* ws = (char*)d_ws;
  // ws layout: [0,4M) bf16 X ; [4M,8M) bf16 X^T ; [8M,16M) Num fp32 ; [16M,+32K) CS fp32
  uint16_t* xb  = (uint16_t*)(ws);
  uint16_t* xtb = (uint16_t*)(ws + (4u  << 20));
  float*    num = (float*)   (ws + (8u  << 20));
  float*    cs  = (float*)   (ws + (16u << 20));

  dim3 cgrid(NPTS/64, DFEAT/64);
  ms_combine<<<cgrid, 256, 0, stream>>>(X, nullptr, nullptr, xb, xtb, 0);
  for (int it = 0; it < 3; ++it) {
    hipMemsetAsync(ws + (8u << 20), 0, (8u << 20) + NPTS*4, stream);
    ms_fused<<<512, 256, 0, stream>>>(xb, xtb, num, cs);
    ms_combine<<<cgrid, 256, 0, stream>>>(num, cs, out + (size_t)it*DFEAT*NPTS,
                                          xb, xtb, 1);
  }
}